// Round 1
// 1875.928 us; speedup vs baseline: 1.0077x; 1.0077x over previous
//
#include <hip/hip_runtime.h>
#include <math.h>

// SPDNet forward, one wave (64 lanes) per batch element.
//
// Round 9: clamp-detection hybrid. rec_mat(X) = U max(lam,1e-4) U^T is the
// IDENTITY when lamMin(X) >= 1e-4. Before each Jacobi eig, run a cheap
// positive-definiteness certificate (Gauss-Jordan elimination with shifted
// diagonal on a scratch copy; full-column updates are valid because the
// trailing submatrix only ever reads trailing rows/cols + the current pivot
// row/col). Pass -> skip the eig entirely and propagate the matrix product
// directly (M2 = w2^T X1 w2 via E=w2^T X1; X3 = w3^T M2 w3). Fail -> the
// original (verified) Jacobi path runs on the pristine matrix.
// Stage-1 test: fp32, shift 5e-4 (margin >> chol backward error ~2e-4).
// Stage-2 test: fp64 (fp32 cannot resolve lamMin~3e-3 vs ||M2||~5e3), shift 2e-4.
// All scratch lives in dead LDS regions: footprint unchanged (~9.6 KB/wave).
//
// Round 8 (kept): bank-aware pair-group <-> lane remap in jac32/jac16.

#define MAXSW32 8
#define MAXSW16 8
#define MAXSW4  8
#define JTOL2   1e-12f
#define DELTA1  5e-4f
#define DELTA2  2e-4

// Compiler-only memory fence (single-wave block: LDS is HW-ordered per wave).
#define CFENCE() asm volatile("" ::: "memory")

__device__ __forceinline__ float shfl_xor_f(float v, int m) { return __shfl_xor(v, m, 64); }
__device__ __forceinline__ float dot4(float4 a, float4 b) {
  return a.x * b.x + a.y * b.y + a.z * b.z + a.w * b.w;
}
__device__ __forceinline__ void axpy4(float4& a, float xv, float4 w) {
  a.x += xv * w.x; a.y += xv * w.y; a.z += xv * w.z; a.w += xv * w.w;
}

// DPP lane-exchange adds (VALU pipe, no DS traffic).
__device__ __forceinline__ float dpp_add_xor1(float d) {
  return d + __int_as_float(__builtin_amdgcn_mov_dpp(__float_as_int(d), 0xB1, 0xF, 0xF, true));
}
__device__ __forceinline__ float dpp_add_xor2(float d) {
  return d + __int_as_float(__builtin_amdgcn_mov_dpp(__float_as_int(d), 0x4E, 0xF, 0xF, true));
}
__device__ __forceinline__ float dpp_add_halfmirror(float d) {  // completes 8-lane sum
  return d + __int_as_float(__builtin_amdgcn_mov_dpp(__float_as_int(d), 0x141, 0xF, 0xF, true));
}

// Jacobi rotation from off-diag dot d and norms dpp,dqq. Divide-free.
__device__ __forceinline__ void rot_cs(float d, float dpp, float dqq,
                                       float& c, float& s) {
  float tau = 0.5f * (dqq - dpp);
  float r   = __builtin_amdgcn_sqrtf(fmaf(tau, tau, d * d));
  float den = fabsf(tau) + r;
  float tnum = __uint_as_float(__float_as_uint(d) ^
                               (__float_as_uint(tau) & 0x80000000u));
  float t = tnum * __builtin_amdgcn_rcpf(den);
  c = __builtin_amdgcn_rsqf(fmaf(t, t, 1.f));
  s = t * c;
}

// One-sided Jacobi, n=32, column stride 36. 16 pairs x 4 lanes.
__device__ __forceinline__ void jac32(float* __restrict__ G, float* __restrict__ nrm,
                                      int lane) {
  const int kq  = lane >> 2, sub = lane & 3;
  // bank-aware group relabel: 0,4,2,6,1,5,3,7 within each 8 (bitrev3)
  const int k = (kq & 8) | ((kq & 1) << 2) | (kq & 2) | ((kq & 4) >> 2);
  const int o0 = 4 * sub, o1 = 4 * sub + 16;
  int pp = (k == 0) ? 31 : k;
  int qq = (k == 0) ? 0 : (31 - k);
  for (int sw = 0; sw < MAXSW32; ++sw) {
    bool anyact = false;
    for (int r = 0; r < 31; ++r) {
      CFENCE();                       // order vs previous round's LDS writes
      const int p = pp, q = qq;
      if (k != 0) { pp += 16; if (pp >= 31) pp -= 31; }
      qq += 16; if (qq >= 31) qq -= 31;
      const int pb = p * 36, qb = q * 36;
      float dpp = nrm[p], dqq = nrm[q];
      float4 gp0 = *(const float4*)(G + pb + o0);
      float4 gp1 = *(const float4*)(G + pb + o1);
      float4 gq0 = *(const float4*)(G + qb + o0);
      float4 gq1 = *(const float4*)(G + qb + o1);
      float d = dot4(gp0, gq0) + dot4(gp1, gq1);
      d = dpp_add_xor1(d);
      d = dpp_add_xor2(d);
      bool active = (d * d > JTOL2 * dpp * dqq);
      if (__ballot(active) == 0ull) continue;
      anyact = true;
      if (active) {
        float c, s;
        rot_cs(d, dpp, dqq, c, s);
        float4 np0, np1, nq0, nq1;
        np0.x = c * gp0.x - s * gq0.x; nq0.x = s * gp0.x + c * gq0.x;
        np0.y = c * gp0.y - s * gq0.y; nq0.y = s * gp0.y + c * gq0.y;
        np0.z = c * gp0.z - s * gq0.z; nq0.z = s * gp0.z + c * gq0.z;
        np0.w = c * gp0.w - s * gq0.w; nq0.w = s * gp0.w + c * gq0.w;
        np1.x = c * gp1.x - s * gq1.x; nq1.x = s * gp1.x + c * gq1.x;
        np1.y = c * gp1.y - s * gq1.y; nq1.y = s * gp1.y + c * gq1.y;
        np1.z = c * gp1.z - s * gq1.z; nq1.z = s * gp1.z + c * gq1.z;
        np1.w = c * gp1.w - s * gq1.w; nq1.w = s * gp1.w + c * gq1.w;
        *(float4*)(G + pb + o0) = np0;
        *(float4*)(G + pb + o1) = np1;
        *(float4*)(G + qb + o0) = nq0;
        *(float4*)(G + qb + o1) = nq1;
        if (sub == 0) {
          float cs2 = 2.f * c * s * d, cc = c * c, ss = s * s;
          nrm[p] = cc * dpp - cs2 + ss * dqq;
          nrm[q] = ss * dpp + cs2 + cc * dqq;
        }
      }
    }
    if (!anyact) break;
  }
  __syncthreads();
}

// One-sided Jacobi, n=16, column stride 20. 8 pairs x 8 lanes.
__device__ __forceinline__ void jac16(float* __restrict__ G, float* __restrict__ nrm,
                                      int lane) {
  const int kq = lane >> 3, sub = lane & 7;
  // bank-aware relabel: adjacent group-pairs spaced 4 (5*4 = 4 mod 8)
  const int k = (kq >> 1) | ((kq & 1) << 2);   // 0,4,1,5,2,6,3,7
  const int o = 2 * sub;
  int pp = (k == 0) ? 15 : k;
  int qq = (k == 0) ? 0 : (15 - k);
  for (int sw = 0; sw < MAXSW16; ++sw) {
    bool anyact = false;
    for (int r = 0; r < 15; ++r) {
      CFENCE();
      const int p = pp, q = qq;
      if (k != 0) { pp += 8; if (pp >= 15) pp -= 15; }
      qq += 8; if (qq >= 15) qq -= 15;
      const int pb = p * 20 + o, qb = q * 20 + o;
      float dpp = nrm[p], dqq = nrm[q];
      float2 gp = *(const float2*)(G + pb);
      float2 gq = *(const float2*)(G + qb);
      float d = gp.x * gq.x + gp.y * gq.y;
      d = dpp_add_xor1(d);
      d = dpp_add_xor2(d);
      d = dpp_add_halfmirror(d);      // sum over the 8-lane group, VALU pipe
      bool active = (d * d > JTOL2 * dpp * dqq);
      if (__ballot(active) == 0ull) continue;
      anyact = true;
      if (active) {
        float c, s;
        rot_cs(d, dpp, dqq, c, s);
        float2 np, nq;
        np.x = c * gp.x - s * gq.x; nq.x = s * gp.x + c * gq.x;
        np.y = c * gp.y - s * gq.y; nq.y = s * gp.y + c * gq.y;
        *(float2*)(G + pb) = np;
        *(float2*)(G + qb) = nq;
        if (sub == 0) {
          float cs2 = 2.f * c * s * d, cc = c * c, ss = s * s;
          nrm[p] = cc * dpp - cs2 + ss * dqq;
          nrm[q] = ss * dpp + cs2 + cc * dqq;
        }
      }
    }
    if (!anyact) break;
  }
  __syncthreads();
}

__launch_bounds__(64)
__global__ void spdnet_kernel(const float* __restrict__ x,
                              const float* __restrict__ w1,
                              const float* __restrict__ w2,
                              const float* __restrict__ w3,
                              const float* __restrict__ fcw,
                              float* __restrict__ out,
                              int B) {
  const int b    = blockIdx.x;
  const int lane = threadIdx.x;

  // R0: x -> L -> X1 (32 cols x 36) -> [M2 (16x20) | F=w2 rowmaj @320 (32x20) | w3s @1024]
  // R1: w1 -> chol32 scratch -> w2s [0..576) + E/Z @576 (32x20) -> Cd (f64 16x20) -> Y@0 + X3@64
  __shared__ __align__(16) float R0[1152];
  __shared__ __align__(16) float R1[1216];
  __shared__ __align__(16) float NRM[32];

  const float* xb = x + (size_t)b * 1024;
  const int kc = lane >> 1, h = lane & 1, hb = h * 16;

  // ---- stage x -> R0, w1 -> R1 (both row-major, stride 36) ----
  #pragma unroll
  for (int t = 0; t < 4; ++t) {
    int i4 = lane + 64 * t;          // float4 index 0..255
    int r = i4 >> 3, c4 = i4 & 7;
    float4 xv = ((const float4*)xb)[i4];
    float4 wv = ((const float4*)w1)[i4];
    *(float4*)(R0 + r * 36 + 4 * c4) = xv;
    *(float4*)(R1 + r * 36 + 4 * c4) = wv;
  }
  float w3r = w3[lane];
  __syncthreads();

  // ---- L = x * w1 in registers: lane (kc,h) owns half-column kc ----
  float4 a0 = {0.f, 0.f, 0.f, 0.f}, a1 = a0, a2 = a0, a3 = a0;
  #pragma unroll
  for (int j = 0; j < 32; ++j) {
    float wv = R1[j * 36 + kc];           // w1[j][kc]
    const float* xc = R0 + j * 36 + hb;   // x[j][i] = x[i][j]
    axpy4(a0, wv, *(const float4*)(xc));
    axpy4(a1, wv, *(const float4*)(xc + 4));
    axpy4(a2, wv, *(const float4*)(xc + 8));
    axpy4(a3, wv, *(const float4*)(xc + 12));
  }
  __syncthreads();                        // all x reads done
  *(float4*)(R0 + kc * 36 + hb)      = a0;
  *(float4*)(R0 + kc * 36 + hb + 4)  = a1;
  *(float4*)(R0 + kc * 36 + hb + 8)  = a2;
  *(float4*)(R0 + kc * 36 + hb + 12) = a3;
  __syncthreads();

  // ---- X1[:,kc] = sum_k w1[k][:] * L[k][kc] ----
  float Lc[32];
  #pragma unroll
  for (int c4 = 0; c4 < 8; ++c4) {
    float4 v = *(const float4*)(R0 + kc * 36 + 4 * c4);
    Lc[4 * c4] = v.x; Lc[4 * c4 + 1] = v.y; Lc[4 * c4 + 2] = v.z; Lc[4 * c4 + 3] = v.w;
  }
  a0 = {0.f, 0.f, 0.f, 0.f}; a1 = a0; a2 = a0; a3 = a0;
  #pragma unroll
  for (int kk = 0; kk < 32; ++kk) {
    float lv = Lc[kk];
    const float* wr = R1 + kk * 36 + hb;  // w1[kk][i]
    axpy4(a0, lv, *(const float4*)(wr));
    axpy4(a1, lv, *(const float4*)(wr + 4));
    axpy4(a2, lv, *(const float4*)(wr + 8));
    axpy4(a3, lv, *(const float4*)(wr + 12));
  }
  float nv = dot4(a0, a0) + dot4(a1, a1) + dot4(a2, a2) + dot4(a3, a3);
  nv += shfl_xor_f(nv, 1);
  __syncthreads();                        // L & w1 reads done
  // write X1 over R0
  *(float4*)(R0 + kc * 36 + hb)      = a0;
  *(float4*)(R0 + kc * 36 + hb + 4)  = a1;
  *(float4*)(R0 + kc * 36 + hb + 8)  = a2;
  *(float4*)(R0 + kc * 36 + hb + 12) = a3;
  if (h == 0) NRM[kc] = nv;
  __syncthreads();                        // X1 + NRM visible

  // ---- chol32 PD certificate on copy of X1 (w1 in R1 is dead) ----
  // Copy X1 -> R1 (stride 36), shift diag by -DELTA1, eliminate.
  #pragma unroll
  for (int c = 0; c < 4; ++c)
    *(float4*)(R1 + kc * 36 + hb + 4 * c) = *(const float4*)(R0 + kc * 36 + hb + 4 * c);
  CFENCE();
  if (lane < 32) R1[lane * 36 + lane] -= DELTA1;
  bool fast1 = true;
  for (int k = 0; k < 32; ++k) {
    CFENCE();
    float d = R1[k * 36 + k];             // uniform read (same address)
    if (!(d > 0.f)) { fast1 = false; break; }
    if (kc > k) {
      float f = R1[kc * 36 + k] * __builtin_amdgcn_rcpf(d);
      float4 u0 = *(const float4*)(R1 + k * 36 + hb);
      float4 u1 = *(const float4*)(R1 + k * 36 + hb + 4);
      float4 u2 = *(const float4*)(R1 + k * 36 + hb + 8);
      float4 u3 = *(const float4*)(R1 + k * 36 + hb + 12);
      float4 v0 = *(float4*)(R1 + kc * 36 + hb);
      float4 v1 = *(float4*)(R1 + kc * 36 + hb + 4);
      float4 v2 = *(float4*)(R1 + kc * 36 + hb + 8);
      float4 v3 = *(float4*)(R1 + kc * 36 + hb + 12);
      axpy4(v0, -f, u0); axpy4(v1, -f, u1);
      axpy4(v2, -f, u2); axpy4(v3, -f, u3);
      *(float4*)(R1 + kc * 36 + hb)      = v0;
      *(float4*)(R1 + kc * 36 + hb + 4)  = v1;
      *(float4*)(R1 + kc * 36 + hb + 8)  = v2;
      *(float4*)(R1 + kc * 36 + hb + 12) = v3;
    }
  }
  __syncthreads();

  // ---- stage w2 into R1[0..576) (over dead chol scratch) ----
  #pragma unroll
  for (int t = 0; t < 8; ++t) {
    int idx = lane + 64 * t;
    int j = idx >> 4, a = idx & 15;
    R1[a * 36 + j] = w2[idx];             // w2 col a contiguous
  }
  __syncthreads();

  if (fast1) {
    // ---- FAST stage 1: rec1 = X1 exactly. E[a][k] = w2_a . x1_k -> R1+576 ----
    float g[16];
    #pragma unroll
    for (int c = 0; c < 4; ++c) {
      float4 v = *(const float4*)(R0 + kc * 36 + hb + 4 * c);
      g[4 * c] = v.x; g[4 * c + 1] = v.y; g[4 * c + 2] = v.z; g[4 * c + 3] = v.w;
    }
    #pragma unroll
    for (int a = 0; a < 16; ++a) {
      const float* wr = R1 + a * 36 + hb;
      float part = 0.f;
      #pragma unroll
      for (int c = 0; c < 4; ++c) {
        float4 wv = *(const float4*)(wr + 4 * c);
        part += g[4 * c] * wv.x + g[4 * c + 1] * wv.y + g[4 * c + 2] * wv.z + g[4 * c + 3] * wv.w;
      }
      part = dpp_add_xor1(part);
      if (h == 0) R1[576 + kc * 20 + a] = part;   // E, same layout as Z
    }
    __syncthreads();                      // all X1 reads done
    // F = w2 row-major (transposed from LDS w2 cols) @ R0+320 stride 20
    #pragma unroll
    for (int t = 0; t < 8; ++t) {
      int idx = lane + 64 * t;
      int j = idx >> 4, a2 = idx & 15;
      R0[320 + j * 20 + a2] = R1[a2 * 36 + j];
    }
    __syncthreads();
  } else {
    // ---- SLOW stage 1: eig #1 + Z ----
    jac32(R0, NRM, lane);
    {
      float g[16];
      #pragma unroll
      for (int c = 0; c < 4; ++c) {
        float4 v = *(const float4*)(R0 + kc * 36 + hb + 4 * c);
        g[4 * c] = v.x; g[4 * c + 1] = v.y; g[4 * c + 2] = v.z; g[4 * c + 3] = v.w;
      }
      float dpp = 0.f;
      #pragma unroll
      for (int i = 0; i < 16; ++i) dpp += g[i] * g[i];
      dpp += shfl_xor_f(dpp, 1);
      float lam = __builtin_amdgcn_sqrtf(dpp);
      float mu  = fmaxf(lam, 1e-4f);
      float sc  = __builtin_amdgcn_sqrtf(mu) * __builtin_amdgcn_rcpf(fmaxf(lam, 1e-30f));
      #pragma unroll
      for (int a = 0; a < 16; ++a) {
        const float* wr = R1 + a * 36 + hb;
        float part = 0.f;
        #pragma unroll
        for (int c = 0; c < 4; ++c) {
          float4 wv = *(const float4*)(wr + 4 * c);
          part += g[4 * c] * wv.x + g[4 * c + 1] * wv.y + g[4 * c + 2] * wv.z + g[4 * c + 3] * wv.w;
        }
        part = dpp_add_xor1(part);
        if (h == 0) R1[576 + kc * 20 + a] = part * sc;
      }
    }
    __syncthreads();
  }

  // ---- M2 (16x16) into R0 stride 20; stage w3 @ R0+1024 ----
  // fast:  M2[a][b] = sum_k E[a][k] * w2[k][b]   (zb from F)
  // slow:  M2[a][b] = sum_k Z[k][a] * Z[k][b]    (zb from Z)
  {
    const int a = lane & 15, b0i = (lane >> 4) * 4;
    const float* zbb = fast1 ? (R0 + 320) : (R1 + 576);
    float m0 = 0.f, m1 = 0.f, m2 = 0.f, m3 = 0.f;
    #pragma unroll
    for (int kk = 0; kk < 32; ++kk) {
      float za = R1[576 + kk * 20 + a];
      float4 zb = *(const float4*)(zbb + kk * 20 + b0i);
      m0 += za * zb.x; m1 += za * zb.y; m2 += za * zb.z; m3 += za * zb.w;
    }
    R0[(b0i + 0) * 20 + a] = m0;
    R0[(b0i + 1) * 20 + a] = m1;
    R0[(b0i + 2) * 20 + a] = m2;
    R0[(b0i + 3) * 20 + a] = m3;
    R0[1024 + (lane & 3) * 20 + (lane >> 2)] = w3r;   // w3 col-major
  }
  __syncthreads();

  // ---- norms of M2 columns (needed by slow path only; cheap) ----
  if (lane < 32) {
    int cc = lane >> 1;
    float4 v0 = *(const float4*)(R0 + cc * 20 + 8 * h);
    float4 v1 = *(const float4*)(R0 + cc * 20 + 8 * h + 4);
    float n2 = dot4(v0, v0) + dot4(v1, v1);
    n2 += shfl_xor_f(n2, 1);
    if (h == 0) NRM[cc] = n2;
  }
  __syncthreads();

  // ---- chol16 PD certificate on M2, in f64 (R1 is dead: 320 doubles) ----
  bool fast2 = true;
  {
    double* Cd = (double*)R1;
    const int c16 = lane >> 2, s4 = (lane & 3) * 4;
    #pragma unroll
    for (int r = 0; r < 4; ++r)
      Cd[c16 * 20 + s4 + r] = (double)R0[c16 * 20 + s4 + r];
    CFENCE();
    if (lane < 16) Cd[lane * 20 + lane] -= DELTA2;
    for (int k = 0; k < 16; ++k) {
      CFENCE();
      double d = Cd[k * 20 + k];          // uniform
      if (!(d > 0.0)) { fast2 = false; break; }
      double rd = 1.0 / d;
      if (c16 > k) {
        double f = Cd[c16 * 20 + k] * rd;
        #pragma unroll
        for (int r = 0; r < 4; ++r)
          Cd[c16 * 20 + s4 + r] -= f * Cd[k * 20 + s4 + r];
      }
    }
  }
  __syncthreads();

  if (fast2) {
    // ---- FAST stage 2: rec2 = M2. Y'[a][k] = w3_a . m2_k; X3 = Y' * w3 ----
    const int k3 = (lane >> 2) & 15, a3 = lane & 3;
    float dotv = 0.f;
    #pragma unroll
    for (int c = 0; c < 4; ++c) {
      float4 gv = *(const float4*)(R0 + k3 * 20 + 4 * c);
      float4 wv = *(const float4*)(R0 + 1024 + a3 * 20 + 4 * c);
      dotv += dot4(gv, wv);
    }
    R1[k3 * 4 + a3] = dotv;               // Y', k-major stride 4 (Cd dead)
    __syncthreads();
    if (lane < 16) {
      int a = lane >> 2, b2 = lane & 3;
      float s = 0.f;
      #pragma unroll
      for (int kk = 0; kk < 16; ++kk)
        s += R1[kk * 4 + a] * R0[1024 + b2 * 20 + kk];   // w3[kk][b2]
      R1[64 + lane] = s;                  // X3
    }
    __syncthreads();
  } else {
    // ---- SLOW stage 2: eig #2 + Y + X3 ----
    jac16(R0, NRM, lane);
    {
      const int k3 = (lane >> 2) & 15, a3 = lane & 3;
      float dpp2 = 0.f, dotv = 0.f;
      #pragma unroll
      for (int c = 0; c < 4; ++c) {
        float4 gv = *(const float4*)(R0 + k3 * 20 + 4 * c);
        float4 wv = *(const float4*)(R0 + 1024 + a3 * 20 + 4 * c);
        dpp2 += dot4(gv, gv);
        dotv += dot4(gv, wv);
      }
      float lam2 = __builtin_amdgcn_sqrtf(dpp2);
      float mu2  = fmaxf(lam2, 1e-4f);
      float sc2  = __builtin_amdgcn_sqrtf(mu2) * __builtin_amdgcn_rcpf(fmaxf(lam2, 1e-30f));
      __syncthreads();                    // M2/w3 reads done before Y write
      R1[k3 * 4 + a3] = dotv * sc2;       // Y, k-major stride 4
    }
    __syncthreads();
    if (lane < 16) {
      int a = lane >> 2, b2 = lane & 3;
      float s = 0.f;
      #pragma unroll
      for (int kk = 0; kk < 16; ++kk)
        s += R1[kk * 4 + a] * R1[kk * 4 + b2];
      R1[64 + lane] = s;                  // X3
    }
    __syncthreads();
  }

  // ---- stage 3: serial 4x4 two-sided Jacobi + LogEig + fc + log_softmax ----
  if (lane == 0) {
    float Am[4][4], V[4][4];
    float maxd = 0.f;
    #pragma unroll
    for (int i = 0; i < 4; ++i) {
      #pragma unroll
      for (int j = 0; j < 4; ++j) {
        Am[i][j] = R1[64 + i * 4 + j];
        V[i][j] = (i == j) ? 1.f : 0.f;
      }
      maxd = fmaxf(maxd, fabsf(Am[i][i]));
    }
    float tol3 = 1e-7f * maxd;
    for (int sw = 0; sw < MAXSW4; ++sw) {
      bool any = false;
      #pragma unroll
      for (int p = 0; p < 3; ++p) {
        #pragma unroll
        for (int q = p + 1; q < 4; ++q) {
          float apq = Am[p][q];
          if (fabsf(apq) > tol3) {
            any = true;
            float c, sv;
            rot_cs(apq, Am[p][p], Am[q][q], c, sv);
            #pragma unroll
            for (int j = 0; j < 4; ++j) {
              float ap = Am[p][j], aq = Am[q][j];
              Am[p][j] = c * ap - sv * aq;
              Am[q][j] = sv * ap + c * aq;
            }
            #pragma unroll
            for (int i = 0; i < 4; ++i) {
              float ap = Am[i][p], aq = Am[i][q];
              Am[i][p] = c * ap - sv * aq;
              Am[i][q] = sv * ap + c * aq;
              float up = V[i][p], uq = V[i][q];
              V[i][p] = c * up - sv * uq;
              V[i][q] = sv * up + c * uq;
            }
          }
        }
      }
      if (!any) break;
    }
    float lm[4];
    #pragma unroll
    for (int i = 0; i < 4; ++i) lm[i] = logf(fmaxf(Am[i][i], 1e-10f));
    float feat[16];
    #pragma unroll
    for (int i = 0; i < 4; ++i)
      #pragma unroll
      for (int j = 0; j < 4; ++j) {
        float acc2 = 0.f;
        #pragma unroll
        for (int kk = 0; kk < 4; ++kk) acc2 += V[i][kk] * lm[kk] * V[j][kk];
        feat[i * 4 + j] = acc2;
      }
    float z0 = 0.f, z1 = 0.f;
    #pragma unroll
    for (int f = 0; f < 16; ++f) {
      z0 += feat[f] * fcw[f * 2 + 0];
      z1 += feat[f] * fcw[f * 2 + 1];
    }
    float mx = fmaxf(z0, z1);
    float lse = mx + logf(expf(z0 - mx) + expf(z1 - mx));
    out[b * 2 + 0] = z0 - lse;
    out[b * 2 + 1] = z1 - lse;
    float* fo = out + (size_t)2 * B + (size_t)b * 16;
    #pragma unroll
    for (int f = 0; f < 16; ++f) fo[f] = feat[f];
  }
}

extern "C" void kernel_launch(void* const* d_in, const int* in_sizes, int n_in,
                              void* d_out, int out_size, void* d_ws, size_t ws_size,
                              hipStream_t stream) {
  (void)n_in; (void)d_ws; (void)ws_size; (void)out_size;
  const float* x   = (const float*)d_in[0];
  const float* w1  = (const float*)d_in[1];
  const float* w2  = (const float*)d_in[2];
  const float* w3  = (const float*)d_in[3];
  const float* fcw = (const float*)d_in[4];
  float* out = (float*)d_out;
  int B = in_sizes[0] / 1024;
  spdnet_kernel<<<B, 64, 0, stream>>>(x, w1, w2, w3, fcw, out, B);
}

// Round 2
// 979.734 us; speedup vs baseline: 1.9294x; 1.9147x over previous
//
#include <hip/hip_runtime.h>
#include <math.h>

// SPDNet forward, one wave (64 lanes) per batch element.
//
// Round 10: partial-spectrum ReEig. Evidence from r9: stage-1 chol certificate
// fails (jac32 still runs; stage-2 certificate passes). So X1's smallest
// eigenvalues sit at/below the 1e-4 clamp. But rec_mat only needs the tiny
// invariant subspace near the clamp: rec1 = X1 + sum_{lam<eps}(eps-lam) u u^T.
// New stage-1 pipeline:
//   1. Gauss-Jordan on A = X1 - 4e-4*I, pivot count m' = #(lam < 4e-4).
//      Raised shift makes fp32 pivot fuzz (~2e-4) safe: miscounts happen only
//      for lam in [2e-4,6e-4], all above eps=1e-4 where correction == 0.
//   2. m'==0  -> rec1 = X1 exactly (fast).
//      1<=m'<=4 -> shift-invert subspace: the SAME GJ pass carries 4 RHS in
//      the stride-36 padding holes (A^{-1}B for free); second GJ pass refines;
//      f64 Gram-Schmidt + Rayleigh-Ritz (4x4 f64 Jacobi, lane 0) gives
//      (theta,u) to <<1e-4; rank-4 correction applied in 16-dim M2 space:
//      M2 += V V^T, V = sqrt(max(eps-theta,0)) * (w2^T Q W).
//      m'>4 or pivot breakdown -> original jac32 (unchanged fallback).
// Stage-2 unchanged: f64 chol certificate (passes) + jac16 fallback.
// All scratch lives in dead LDS (holes / NRM / R0[960..1024)): footprint and
// occupancy unchanged (~9.6 KB/wave, 16 waves/CU).

#define MAXSW32 8
#define MAXSW16 8
#define MAXSW4  8
#define JTOL2   1e-12f
#define EPS_REC 1e-4f
#define SHIFT1  4e-4f
#define BRKTOL  1e-7f
#define DELTA2  2e-4

// Compiler-only memory fence (single-wave block: LDS is HW-ordered per wave).
#define CFENCE() asm volatile("" ::: "memory")

__device__ __forceinline__ float shfl_xor_f(float v, int m) { return __shfl_xor(v, m, 64); }
__device__ __forceinline__ float dot4(float4 a, float4 b) {
  return a.x * b.x + a.y * b.y + a.z * b.z + a.w * b.w;
}
__device__ __forceinline__ void axpy4(float4& a, float xv, float4 w) {
  a.x += xv * w.x; a.y += xv * w.y; a.z += xv * w.z; a.w += xv * w.w;
}

// DPP lane-exchange adds (VALU pipe, no DS traffic).
__device__ __forceinline__ float dpp_add_xor1(float d) {
  return d + __int_as_float(__builtin_amdgcn_mov_dpp(__float_as_int(d), 0xB1, 0xF, 0xF, true));
}
__device__ __forceinline__ float dpp_add_xor2(float d) {
  return d + __int_as_float(__builtin_amdgcn_mov_dpp(__float_as_int(d), 0x4E, 0xF, 0xF, true));
}
__device__ __forceinline__ float dpp_add_halfmirror(float d) {  // completes 8-lane sum
  return d + __int_as_float(__builtin_amdgcn_mov_dpp(__float_as_int(d), 0x141, 0xF, 0xF, true));
}

// f64 sum over lanes 0..31 (callers keep sources within the active half).
__device__ __forceinline__ double wsum32(double v) {
  #pragma unroll
  for (int m = 1; m <= 16; m <<= 1) v += __shfl_xor(v, m, 64);
  return v;
}
__device__ __forceinline__ float wmax64(float v) {
  #pragma unroll
  for (int m = 1; m <= 32; m <<= 1) v = fmaxf(v, __shfl_xor(v, m, 64));
  return v;
}

// Jacobi rotation from off-diag dot d and norms dpp,dqq. Divide-free.
__device__ __forceinline__ void rot_cs(float d, float dpp, float dqq,
                                       float& c, float& s) {
  float tau = 0.5f * (dqq - dpp);
  float r   = __builtin_amdgcn_sqrtf(fmaf(tau, tau, d * d));
  float den = fabsf(tau) + r;
  float tnum = __uint_as_float(__float_as_uint(d) ^
                               (__float_as_uint(tau) & 0x80000000u));
  float t = tnum * __builtin_amdgcn_rcpf(den);
  c = __builtin_amdgcn_rsqf(fmaf(t, t, 1.f));
  s = t * c;
}

// Gauss-Jordan elimination of A = X1 - SHIFT1*I (32x32, stride 36) with 4 RHS
// carried in the padding holes (cols 32..35). On exit: diag = pivots, holes =
// C with solution Y = diag^{-1} C. mneg = #(pivots<=0); brk on tiny/NaN pivot.
// pass2: RHS = previous solution (holes/diag) instead of hash init.
__device__ __forceinline__ void gj_pass(const float* __restrict__ X1,
                                        float* __restrict__ A,
                                        int lane, float maxd, bool pass2,
                                        int& mneg, bool& brk) {
  const int kc = lane >> 1, h = lane & 1, hb = h * 16;
  float4 yv = {0.f, 0.f, 0.f, 0.f};
  if (pass2) {
    float r = __builtin_amdgcn_rcpf(A[kc * 36 + kc]);
    float4 cv = *(const float4*)(A + kc * 36 + 32);
    yv.x = cv.x * r; yv.y = cv.y * r; yv.z = cv.z * r; yv.w = cv.w * r;
  }
  CFENCE();
  #pragma unroll
  for (int c = 0; c < 4; ++c)
    *(float4*)(A + kc * 36 + hb + 4 * c) = *(const float4*)(X1 + kc * 36 + hb + 4 * c);
  if (h == 1) {
    float4 bv;
    if (pass2) bv = yv;
    else {
      unsigned s = kc * 0x9E3779B9u + 0x7F4A7C15u;
      s = s * 1664525u + 1013904223u; bv.x = (float)(int)(s >> 16) - 32768.f;
      s = s * 1664525u + 1013904223u; bv.y = (float)(int)(s >> 16) - 32768.f;
      s = s * 1664525u + 1013904223u; bv.z = (float)(int)(s >> 16) - 32768.f;
      s = s * 1664525u + 1013904223u; bv.w = (float)(int)(s >> 16) - 32768.f;
    }
    *(float4*)(A + kc * 36 + 32) = bv;
  }
  CFENCE();
  if (lane < 32) A[lane * 36 + lane] -= SHIFT1;
  mneg = 0; brk = false;
  for (int k = 0; k < 32; ++k) {
    CFENCE();
    float d = A[k * 36 + k];                  // uniform read
    if (d <= 0.f) ++mneg;
    if (!(fabsf(d) >= BRKTOL * maxd)) { brk = true; break; }  // also NaN
    float f = A[kc * 36 + k] * __builtin_amdgcn_rcpf(d);
    if (kc != k) {
      const float* rk = A + k * 36 + hb;
      float* rc = A + kc * 36 + hb;
      #pragma unroll
      for (int c = 0; c < 4; ++c) {
        float4 u = *(const float4*)(rk + 4 * c);
        float4 v = *(float4*)(rc + 4 * c);
        axpy4(v, -f, u);
        *(float4*)(rc + 4 * c) = v;
      }
      if (h == 1) {
        float4 u = *(const float4*)(A + k * 36 + 32);
        float4 v = *(float4*)(A + kc * 36 + 32);
        axpy4(v, -f, u);
        *(float4*)(A + kc * 36 + 32) = v;
      }
    }
  }
}

// One-sided Jacobi, n=32, column stride 36. 16 pairs x 4 lanes.
__device__ __forceinline__ void jac32(float* __restrict__ G, float* __restrict__ nrm,
                                      int lane) {
  const int kq  = lane >> 2, sub = lane & 3;
  const int k = (kq & 8) | ((kq & 1) << 2) | (kq & 2) | ((kq & 4) >> 2);
  const int o0 = 4 * sub, o1 = 4 * sub + 16;
  int pp = (k == 0) ? 31 : k;
  int qq = (k == 0) ? 0 : (31 - k);
  for (int sw = 0; sw < MAXSW32; ++sw) {
    bool anyact = false;
    for (int r = 0; r < 31; ++r) {
      CFENCE();
      const int p = pp, q = qq;
      if (k != 0) { pp += 16; if (pp >= 31) pp -= 31; }
      qq += 16; if (qq >= 31) qq -= 31;
      const int pb = p * 36, qb = q * 36;
      float dpp = nrm[p], dqq = nrm[q];
      float4 gp0 = *(const float4*)(G + pb + o0);
      float4 gp1 = *(const float4*)(G + pb + o1);
      float4 gq0 = *(const float4*)(G + qb + o0);
      float4 gq1 = *(const float4*)(G + qb + o1);
      float d = dot4(gp0, gq0) + dot4(gp1, gq1);
      d = dpp_add_xor1(d);
      d = dpp_add_xor2(d);
      bool active = (d * d > JTOL2 * dpp * dqq);
      if (__ballot(active) == 0ull) continue;
      anyact = true;
      if (active) {
        float c, s;
        rot_cs(d, dpp, dqq, c, s);
        float4 np0, np1, nq0, nq1;
        np0.x = c * gp0.x - s * gq0.x; nq0.x = s * gp0.x + c * gq0.x;
        np0.y = c * gp0.y - s * gq0.y; nq0.y = s * gp0.y + c * gq0.y;
        np0.z = c * gp0.z - s * gq0.z; nq0.z = s * gp0.z + c * gq0.z;
        np0.w = c * gp0.w - s * gq0.w; nq0.w = s * gp0.w + c * gq0.w;
        np1.x = c * gp1.x - s * gq1.x; nq1.x = s * gp1.x + c * gq1.x;
        np1.y = c * gp1.y - s * gq1.y; nq1.y = s * gp1.y + c * gq1.y;
        np1.z = c * gp1.z - s * gq1.z; nq1.z = s * gp1.z + c * gq1.z;
        np1.w = c * gp1.w - s * gq1.w; nq1.w = s * gp1.w + c * gq1.w;
        *(float4*)(G + pb + o0) = np0;
        *(float4*)(G + pb + o1) = np1;
        *(float4*)(G + qb + o0) = nq0;
        *(float4*)(G + qb + o1) = nq1;
        if (sub == 0) {
          float cs2 = 2.f * c * s * d, cc = c * c, ss = s * s;
          nrm[p] = cc * dpp - cs2 + ss * dqq;
          nrm[q] = ss * dpp + cs2 + cc * dqq;
        }
      }
    }
    if (!anyact) break;
  }
  __syncthreads();
}

// One-sided Jacobi, n=16, column stride 20. 8 pairs x 8 lanes.
__device__ __forceinline__ void jac16(float* __restrict__ G, float* __restrict__ nrm,
                                      int lane) {
  const int kq = lane >> 3, sub = lane & 7;
  const int k = (kq >> 1) | ((kq & 1) << 2);   // 0,4,1,5,2,6,3,7
  const int o = 2 * sub;
  int pp = (k == 0) ? 15 : k;
  int qq = (k == 0) ? 0 : (15 - k);
  for (int sw = 0; sw < MAXSW16; ++sw) {
    bool anyact = false;
    for (int r = 0; r < 15; ++r) {
      CFENCE();
      const int p = pp, q = qq;
      if (k != 0) { pp += 8; if (pp >= 15) pp -= 15; }
      qq += 8; if (qq >= 15) qq -= 15;
      const int pb = p * 20 + o, qb = q * 20 + o;
      float dpp = nrm[p], dqq = nrm[q];
      float2 gp = *(const float2*)(G + pb);
      float2 gq = *(const float2*)(G + qb);
      float d = gp.x * gq.x + gp.y * gq.y;
      d = dpp_add_xor1(d);
      d = dpp_add_xor2(d);
      d = dpp_add_halfmirror(d);
      bool active = (d * d > JTOL2 * dpp * dqq);
      if (__ballot(active) == 0ull) continue;
      anyact = true;
      if (active) {
        float c, s;
        rot_cs(d, dpp, dqq, c, s);
        float2 np, nq;
        np.x = c * gp.x - s * gq.x; nq.x = s * gp.x + c * gq.x;
        np.y = c * gp.y - s * gq.y; nq.y = s * gp.y + c * gq.y;
        *(float2*)(G + pb) = np;
        *(float2*)(G + qb) = nq;
        if (sub == 0) {
          float cs2 = 2.f * c * s * d, cc = c * c, ss = s * s;
          nrm[p] = cc * dpp - cs2 + ss * dqq;
          nrm[q] = ss * dpp + cs2 + cc * dqq;
        }
      }
    }
    if (!anyact) break;
  }
  __syncthreads();
}

__launch_bounds__(64)
__global__ void spdnet_kernel(const float* __restrict__ x,
                              const float* __restrict__ w1,
                              const float* __restrict__ w2,
                              const float* __restrict__ w3,
                              const float* __restrict__ fcw,
                              float* __restrict__ out,
                              int B) {
  const int b    = blockIdx.x;
  const int lane = threadIdx.x;

  // R0: x -> L -> X1 (32x36 rows+holes) -> [M2 16x20 | F 32x20 @320 | V/TQ @960 | w3s @1024]
  // R1: w1 -> GJ scratch (A + RHS holes, Q in holes) -> w2s [0..576) + E/Z @576
  __shared__ __align__(16) float R0[1152];
  __shared__ __align__(16) float R1[1216];
  __shared__ __align__(16) float NRM[32];

  const float* xb = x + (size_t)b * 1024;
  const int kc = lane >> 1, h = lane & 1, hb = h * 16;

  // ---- stage x -> R0, w1 -> R1 (both row-major, stride 36) ----
  #pragma unroll
  for (int t = 0; t < 4; ++t) {
    int i4 = lane + 64 * t;
    int r = i4 >> 3, c4 = i4 & 7;
    float4 xv = ((const float4*)xb)[i4];
    float4 wv = ((const float4*)w1)[i4];
    *(float4*)(R0 + r * 36 + 4 * c4) = xv;
    *(float4*)(R1 + r * 36 + 4 * c4) = wv;
  }
  float w3r = w3[lane];
  __syncthreads();

  // ---- L = x * w1 in registers: lane (kc,h) owns half-column kc ----
  float4 a0 = {0.f, 0.f, 0.f, 0.f}, a1 = a0, a2 = a0, a3 = a0;
  #pragma unroll
  for (int j = 0; j < 32; ++j) {
    float wv = R1[j * 36 + kc];
    const float* xc = R0 + j * 36 + hb;
    axpy4(a0, wv, *(const float4*)(xc));
    axpy4(a1, wv, *(const float4*)(xc + 4));
    axpy4(a2, wv, *(const float4*)(xc + 8));
    axpy4(a3, wv, *(const float4*)(xc + 12));
  }
  __syncthreads();
  *(float4*)(R0 + kc * 36 + hb)      = a0;
  *(float4*)(R0 + kc * 36 + hb + 4)  = a1;
  *(float4*)(R0 + kc * 36 + hb + 8)  = a2;
  *(float4*)(R0 + kc * 36 + hb + 12) = a3;
  __syncthreads();

  // ---- X1[:,kc] = sum_k w1[k][:] * L[k][kc] ----
  float Lc[32];
  #pragma unroll
  for (int c4 = 0; c4 < 8; ++c4) {
    float4 v = *(const float4*)(R0 + kc * 36 + 4 * c4);
    Lc[4 * c4] = v.x; Lc[4 * c4 + 1] = v.y; Lc[4 * c4 + 2] = v.z; Lc[4 * c4 + 3] = v.w;
  }
  a0 = {0.f, 0.f, 0.f, 0.f}; a1 = a0; a2 = a0; a3 = a0;
  #pragma unroll
  for (int kk = 0; kk < 32; ++kk) {
    float lv = Lc[kk];
    const float* wr = R1 + kk * 36 + hb;
    axpy4(a0, lv, *(const float4*)(wr));
    axpy4(a1, lv, *(const float4*)(wr + 4));
    axpy4(a2, lv, *(const float4*)(wr + 8));
    axpy4(a3, lv, *(const float4*)(wr + 12));
  }
  float nv = dot4(a0, a0) + dot4(a1, a1) + dot4(a2, a2) + dot4(a3, a3);
  nv += shfl_xor_f(nv, 1);
  __syncthreads();
  *(float4*)(R0 + kc * 36 + hb)      = a0;
  *(float4*)(R0 + kc * 36 + hb + 4)  = a1;
  *(float4*)(R0 + kc * 36 + hb + 8)  = a2;
  *(float4*)(R0 + kc * 36 + hb + 12) = a3;
  if (h == 0) NRM[kc] = nv;
  __syncthreads();

  // ---- inertia + shift-invert pass 1 ----
  float maxd = wmax64(R0[kc * 36 + kc]);
  int mneg; bool brk;
  gj_pass(R0, R1, lane, maxd, false, mneg, brk);
  const bool doeig  = brk || (mneg > 4);
  const bool docorr = !doeig && (mneg >= 1);

  if (docorr) {
    // ---- pass 2 (refine), then f64 GS + Rayleigh-Ritz on the 4-dim block ----
    int mn2; bool b2;
    gj_pass(R0, R1, lane, maxd, true, mn2, b2);
    (void)mn2; (void)b2;
    if (lane < 32) {
      const int j = lane;
      float r = __builtin_amdgcn_rcpf(R1[j * 36 + j]);
      float4 cv = *(const float4*)(R1 + j * 36 + 32);
      double y0 = (double)(cv.x * r), y1 = (double)(cv.y * r);
      double y2 = (double)(cv.z * r), y3 = (double)(cv.w * r);
      double n, pr;
      double q0, q1, q2, q3;
      n = wsum32(y0 * y0); q0 = y0 * (1.0 / sqrt(n + 1e-280));
      pr = wsum32(q0 * y1); y1 -= pr * q0;
      n = wsum32(y1 * y1); q1 = y1 * (1.0 / sqrt(n + 1e-280));
      pr = wsum32(q0 * y2); y2 -= pr * q0;
      pr = wsum32(q1 * y2); y2 -= pr * q1;
      n = wsum32(y2 * y2); q2 = y2 * (1.0 / sqrt(n + 1e-280));
      pr = wsum32(q0 * y3); y3 -= pr * q0;
      pr = wsum32(q1 * y3); y3 -= pr * q1;
      pr = wsum32(q2 * y3); y3 -= pr * q2;
      n = wsum32(y3 * y3); q3 = y3 * (1.0 / sqrt(n + 1e-280));
      CFENCE();
      *(float4*)(R1 + j * 36 + 32) =
          make_float4((float)q0, (float)q1, (float)q2, (float)q3);
      CFENCE();
      // T = X1 * Q (f64 accumulation; X1 symmetric so use row j)
      double T0 = 0, T1 = 0, T2 = 0, T3 = 0;
      #pragma unroll 4
      for (int i = 0; i < 32; ++i) {
        float4 qv = *(const float4*)(R1 + i * 36 + 32);   // uniform -> broadcast
        double xji = (double)R0[j * 36 + i];
        T0 += xji * qv.x; T1 += xji * qv.y; T2 += xji * qv.z; T3 += xji * qv.w;
      }
      double S00 = wsum32(q0 * T0), S10 = wsum32(q1 * T0);
      double S20 = wsum32(q2 * T0), S30 = wsum32(q3 * T0);
      double S11 = wsum32(q1 * T1), S21 = wsum32(q2 * T1), S31 = wsum32(q3 * T1);
      double S22 = wsum32(q2 * T2), S32 = wsum32(q3 * T2);
      double S33 = wsum32(q3 * T3);
      if (lane == 0) {
        double Ad[4][4] = {{S00, S10, S20, S30}, {S10, S11, S21, S31},
                           {S20, S21, S22, S32}, {S30, S31, S32, S33}};
        float Wd[4][4] = {{1.f, 0.f, 0.f, 0.f}, {0.f, 1.f, 0.f, 0.f},
                          {0.f, 0.f, 1.f, 0.f}, {0.f, 0.f, 0.f, 1.f}};
        for (int sw = 0; sw < 5; ++sw) {
          #pragma unroll
          for (int p = 0; p < 3; ++p) {
            #pragma unroll
            for (int q = p + 1; q < 4; ++q) {
              double apq = Ad[p][q];
              if (fabs(apq) > 1e-14 * (fabs(Ad[p][p]) + fabs(Ad[q][q])) + 1e-300) {
                double tau = 0.5 * (Ad[q][q] - Ad[p][p]);
                double rr = sqrt(tau * tau + apq * apq);
                double t = ((tau >= 0.0) ? apq : -apq) / (fabs(tau) + rr);
                double c = 1.0 / sqrt(t * t + 1.0), sv = t * c;
                #pragma unroll
                for (int jj = 0; jj < 4; ++jj) {
                  double ap = Ad[p][jj], aq = Ad[q][jj];
                  Ad[p][jj] = c * ap - sv * aq;
                  Ad[q][jj] = sv * ap + c * aq;
                }
                #pragma unroll
                for (int ii = 0; ii < 4; ++ii) {
                  double ap = Ad[ii][p], aq = Ad[ii][q];
                  Ad[ii][p] = c * ap - sv * aq;
                  Ad[ii][q] = sv * ap + c * aq;
                  float wp = Wd[ii][p], wq = Wd[ii][q];
                  Wd[ii][p] = (float)(c * wp - sv * wq);
                  Wd[ii][q] = (float)(sv * wp + c * wq);
                }
              }
            }
          }
        }
        #pragma unroll
        for (int qi = 0; qi < 4; ++qi) {
          NRM[16 + qi] = (float)Ad[qi][qi];        // theta
          #pragma unroll
          for (int ai = 0; ai < 4; ++ai) NRM[ai * 4 + qi] = Wd[ai][qi];
        }
      }
    }
    __syncthreads();
  }

  if (doeig) {
    // ---- fallback: full one-sided Jacobi on X1 (NRM intact) ----
    jac32(R0, NRM, lane);
  }

  // ---- stage w2 into R1[0..576) (GJ scratch rows dead; holes survive) ----
  #pragma unroll
  for (int t = 0; t < 8; ++t) {
    int idx = lane + 64 * t;
    int j = idx >> 4, a = idx & 15;
    R1[a * 36 + j] = w2[idx];
  }
  __syncthreads();

  if (!doeig) {
    // ---- TQ = w2^T Q (regs; Q holes + w2 both in R1, disjoint) ----
    float tq = 0.f;
    if (docorr) {
      const int aq = lane >> 4, a16 = lane & 15;
      #pragma unroll 4
      for (int j = 0; j < 32; ++j)
        tq += R1[a16 * 36 + j] * R1[j * 36 + 32 + aq];
      CFENCE();
    }
    // ---- E[a][k] = w2_a . x1_k -> R1+576 (rec1 base = X1) ----
    {
      float g[16];
      #pragma unroll
      for (int c = 0; c < 4; ++c) {
        float4 v = *(const float4*)(R0 + kc * 36 + hb + 4 * c);
        g[4 * c] = v.x; g[4 * c + 1] = v.y; g[4 * c + 2] = v.z; g[4 * c + 3] = v.w;
      }
      #pragma unroll
      for (int a = 0; a < 16; ++a) {
        const float* wr = R1 + a * 36 + hb;
        float part = 0.f;
        #pragma unroll
        for (int c = 0; c < 4; ++c) {
          float4 wv = *(const float4*)(wr + 4 * c);
          part += g[4 * c] * wv.x + g[4 * c + 1] * wv.y + g[4 * c + 2] * wv.z + g[4 * c + 3] * wv.w;
        }
        part = dpp_add_xor1(part);
        if (h == 0) R1[576 + kc * 20 + a] = part;
      }
    }
    __syncthreads();                      // all X1 reads done
    if (docorr) {
      // ---- V[a][q] = sqrt((eps-theta_q)+) * sum_aq TQ[a][aq] W[aq][q] ----
      R0[960 + lane] = tq;                // TQ[a16][aq] @ 960+aq*16+a16
      CFENCE();
      if (lane < 16) {
        float t0 = R0[960 + lane], t1 = R0[976 + lane];
        float t2 = R0[992 + lane], t3 = R0[1008 + lane];
        float4 vv;
        {
          float cs = __builtin_amdgcn_sqrtf(fmaxf(EPS_REC - NRM[16], 0.f));
          vv.x = cs * (t0 * NRM[0] + t1 * NRM[4] + t2 * NRM[8] + t3 * NRM[12]);
        }
        {
          float cs = __builtin_amdgcn_sqrtf(fmaxf(EPS_REC - NRM[17], 0.f));
          vv.y = cs * (t0 * NRM[1] + t1 * NRM[5] + t2 * NRM[9] + t3 * NRM[13]);
        }
        {
          float cs = __builtin_amdgcn_sqrtf(fmaxf(EPS_REC - NRM[18], 0.f));
          vv.z = cs * (t0 * NRM[2] + t1 * NRM[6] + t2 * NRM[10] + t3 * NRM[14]);
        }
        {
          float cs = __builtin_amdgcn_sqrtf(fmaxf(EPS_REC - NRM[19], 0.f));
          vv.w = cs * (t0 * NRM[3] + t1 * NRM[7] + t2 * NRM[11] + t3 * NRM[15]);
        }
        CFENCE();
        *(float4*)(R0 + 960 + lane * 4) = vv;   // V rows, float4 each
      }
      CFENCE();
    }
    // ---- F = w2 row-major @ R0+320 (X1 dead now) ----
    #pragma unroll
    for (int t = 0; t < 8; ++t) {
      int idx = lane + 64 * t;
      int j = idx >> 4, a2 = idx & 15;
      R0[320 + j * 20 + a2] = R1[a2 * 36 + j];
    }
    __syncthreads();
  } else {
    // ---- SLOW stage 1: Z[:,k] = (w2^T g_k) * sqrt(mu)/lam ----
    {
      float g[16];
      #pragma unroll
      for (int c = 0; c < 4; ++c) {
        float4 v = *(const float4*)(R0 + kc * 36 + hb + 4 * c);
        g[4 * c] = v.x; g[4 * c + 1] = v.y; g[4 * c + 2] = v.z; g[4 * c + 3] = v.w;
      }
      float dpp = 0.f;
      #pragma unroll
      for (int i = 0; i < 16; ++i) dpp += g[i] * g[i];
      dpp += shfl_xor_f(dpp, 1);
      float lam = __builtin_amdgcn_sqrtf(dpp);
      float mu  = fmaxf(lam, 1e-4f);
      float sc  = __builtin_amdgcn_sqrtf(mu) * __builtin_amdgcn_rcpf(fmaxf(lam, 1e-30f));
      #pragma unroll
      for (int a = 0; a < 16; ++a) {
        const float* wr = R1 + a * 36 + hb;
        float part = 0.f;
        #pragma unroll
        for (int c = 0; c < 4; ++c) {
          float4 wv = *(const float4*)(wr + 4 * c);
          part += g[4 * c] * wv.x + g[4 * c + 1] * wv.y + g[4 * c + 2] * wv.z + g[4 * c + 3] * wv.w;
        }
        part = dpp_add_xor1(part);
        if (h == 0) R1[576 + kc * 20 + a] = part * sc;
      }
    }
    __syncthreads();
  }

  // ---- M2 (16x16) into R0 stride 20 (+rank-4 correction); stage w3 @1024 ----
  {
    const int a = lane & 15, b0i = (lane >> 4) * 4;
    const float* zbb = doeig ? (R1 + 576) : (R0 + 320);
    float m0 = 0.f, m1 = 0.f, m2 = 0.f, m3 = 0.f;
    #pragma unroll
    for (int kk = 0; kk < 32; ++kk) {
      float za = R1[576 + kk * 20 + a];
      float4 zb = *(const float4*)(zbb + kk * 20 + b0i);
      m0 += za * zb.x; m1 += za * zb.y; m2 += za * zb.z; m3 += za * zb.w;
    }
    if (docorr) {
      float4 va = *(const float4*)(R0 + 960 + a * 4);
      float4 v0 = *(const float4*)(R0 + 960 + (b0i + 0) * 4);
      float4 v1 = *(const float4*)(R0 + 960 + (b0i + 1) * 4);
      float4 v2 = *(const float4*)(R0 + 960 + (b0i + 2) * 4);
      float4 v3 = *(const float4*)(R0 + 960 + (b0i + 3) * 4);
      m0 += dot4(va, v0); m1 += dot4(va, v1);
      m2 += dot4(va, v2); m3 += dot4(va, v3);
    }
    R0[(b0i + 0) * 20 + a] = m0;
    R0[(b0i + 1) * 20 + a] = m1;
    R0[(b0i + 2) * 20 + a] = m2;
    R0[(b0i + 3) * 20 + a] = m3;
    R0[1024 + (lane & 3) * 20 + (lane >> 2)] = w3r;   // w3 col-major
  }
  __syncthreads();

  // ---- norms of M2 columns (slow path needs them; cheap) ----
  if (lane < 32) {
    int cc = lane >> 1;
    float4 v0 = *(const float4*)(R0 + cc * 20 + 8 * h);
    float4 v1 = *(const float4*)(R0 + cc * 20 + 8 * h + 4);
    float n2 = dot4(v0, v0) + dot4(v1, v1);
    n2 += shfl_xor_f(n2, 1);
    if (h == 0) NRM[cc] = n2;
  }
  __syncthreads();

  // ---- chol16 PD certificate on M2, f64 (R1 dead: 320 doubles) ----
  bool fast2 = true;
  {
    double* Cd = (double*)R1;
    const int c16 = lane >> 2, s4 = (lane & 3) * 4;
    #pragma unroll
    for (int r = 0; r < 4; ++r)
      Cd[c16 * 20 + s4 + r] = (double)R0[c16 * 20 + s4 + r];
    CFENCE();
    if (lane < 16) Cd[lane * 20 + lane] -= DELTA2;
    for (int k = 0; k < 16; ++k) {
      CFENCE();
      double d = Cd[k * 20 + k];
      if (!(d > 0.0)) { fast2 = false; break; }
      double rd = 1.0 / d;
      if (c16 > k) {
        double f = Cd[c16 * 20 + k] * rd;
        #pragma unroll
        for (int r = 0; r < 4; ++r)
          Cd[c16 * 20 + s4 + r] -= f * Cd[k * 20 + s4 + r];
      }
    }
  }
  __syncthreads();

  if (fast2) {
    // ---- FAST stage 2: rec2 = M2. Y'[a][k] = w3_a . m2_k; X3 = Y' * w3 ----
    const int k3 = (lane >> 2) & 15, a3 = lane & 3;
    float dotv = 0.f;
    #pragma unroll
    for (int c = 0; c < 4; ++c) {
      float4 gv = *(const float4*)(R0 + k3 * 20 + 4 * c);
      float4 wv = *(const float4*)(R0 + 1024 + a3 * 20 + 4 * c);
      dotv += dot4(gv, wv);
    }
    R1[k3 * 4 + a3] = dotv;
    __syncthreads();
    if (lane < 16) {
      int a = lane >> 2, b2 = lane & 3;
      float s = 0.f;
      #pragma unroll
      for (int kk = 0; kk < 16; ++kk)
        s += R1[kk * 4 + a] * R0[1024 + b2 * 20 + kk];
      R1[64 + lane] = s;
    }
    __syncthreads();
  } else {
    // ---- SLOW stage 2: eig #2 + Y + X3 ----
    jac16(R0, NRM, lane);
    {
      const int k3 = (lane >> 2) & 15, a3 = lane & 3;
      float dpp2 = 0.f, dotv = 0.f;
      #pragma unroll
      for (int c = 0; c < 4; ++c) {
        float4 gv = *(const float4*)(R0 + k3 * 20 + 4 * c);
        float4 wv = *(const float4*)(R0 + 1024 + a3 * 20 + 4 * c);
        dpp2 += dot4(gv, gv);
        dotv += dot4(gv, wv);
      }
      float lam2 = __builtin_amdgcn_sqrtf(dpp2);
      float mu2  = fmaxf(lam2, 1e-4f);
      float sc2  = __builtin_amdgcn_sqrtf(mu2) * __builtin_amdgcn_rcpf(fmaxf(lam2, 1e-30f));
      __syncthreads();
      R1[k3 * 4 + a3] = dotv * sc2;
    }
    __syncthreads();
    if (lane < 16) {
      int a = lane >> 2, b2 = lane & 3;
      float s = 0.f;
      #pragma unroll
      for (int kk = 0; kk < 16; ++kk)
        s += R1[kk * 4 + a] * R1[kk * 4 + b2];
      R1[64 + lane] = s;
    }
    __syncthreads();
  }

  // ---- stage 3: serial 4x4 two-sided Jacobi + LogEig + fc + log_softmax ----
  if (lane == 0) {
    float Am[4][4], V[4][4];
    float maxdg = 0.f;
    #pragma unroll
    for (int i = 0; i < 4; ++i) {
      #pragma unroll
      for (int j = 0; j < 4; ++j) {
        Am[i][j] = R1[64 + i * 4 + j];
        V[i][j] = (i == j) ? 1.f : 0.f;
      }
      maxdg = fmaxf(maxdg, fabsf(Am[i][i]));
    }
    float tol3 = 1e-7f * maxdg;
    for (int sw = 0; sw < MAXSW4; ++sw) {
      bool any = false;
      #pragma unroll
      for (int p = 0; p < 3; ++p) {
        #pragma unroll
        for (int q = p + 1; q < 4; ++q) {
          float apq = Am[p][q];
          if (fabsf(apq) > tol3) {
            any = true;
            float c, sv;
            rot_cs(apq, Am[p][p], Am[q][q], c, sv);
            #pragma unroll
            for (int j = 0; j < 4; ++j) {
              float ap = Am[p][j], aq = Am[q][j];
              Am[p][j] = c * ap - sv * aq;
              Am[q][j] = sv * ap + c * aq;
            }
            #pragma unroll
            for (int i = 0; i < 4; ++i) {
              float ap = Am[i][p], aq = Am[i][q];
              Am[i][p] = c * ap - sv * aq;
              Am[i][q] = sv * ap + c * aq;
              float up = V[i][p], uq = V[i][q];
              V[i][p] = c * up - sv * uq;
              V[i][q] = sv * up + c * uq;
            }
          }
        }
      }
      if (!any) break;
    }
    float lm[4];
    #pragma unroll
    for (int i = 0; i < 4; ++i) lm[i] = logf(fmaxf(Am[i][i], 1e-10f));
    float feat[16];
    #pragma unroll
    for (int i = 0; i < 4; ++i)
      #pragma unroll
      for (int j = 0; j < 4; ++j) {
        float acc2 = 0.f;
        #pragma unroll
        for (int kk = 0; kk < 4; ++kk) acc2 += V[i][kk] * lm[kk] * V[j][kk];
        feat[i * 4 + j] = acc2;
      }
    float z0 = 0.f, z1 = 0.f;
    #pragma unroll
    for (int f = 0; f < 16; ++f) {
      z0 += feat[f] * fcw[f * 2 + 0];
      z1 += feat[f] * fcw[f * 2 + 1];
    }
    float mx = fmaxf(z0, z1);
    float lse = mx + logf(expf(z0 - mx) + expf(z1 - mx));
    out[b * 2 + 0] = z0 - lse;
    out[b * 2 + 1] = z1 - lse;
    float* fo = out + (size_t)2 * B + (size_t)b * 16;
    #pragma unroll
    for (int f = 0; f < 16; ++f) fo[f] = feat[f];
  }
}

extern "C" void kernel_launch(void* const* d_in, const int* in_sizes, int n_in,
                              void* d_out, int out_size, void* d_ws, size_t ws_size,
                              hipStream_t stream) {
  (void)n_in; (void)d_ws; (void)ws_size; (void)out_size;
  const float* x   = (const float*)d_in[0];
  const float* w1  = (const float*)d_in[1];
  const float* w2  = (const float*)d_in[2];
  const float* w3  = (const float*)d_in[3];
  const float* fcw = (const float*)d_in[4];
  float* out = (float*)d_out;
  int B = in_sizes[0] / 1024;
  spdnet_kernel<<<B, 64, 0, stream>>>(x, w1, w2, w3, fcw, out, B);
}

// Round 3
// 797.555 us; speedup vs baseline: 2.3702x; 1.2284x over previous
//
#include <hip/hip_runtime.h>
#include <math.h>

// SPDNet forward, one wave (64 lanes) per batch element.
//
// Round 11: register-resident Gauss-Jordan. r10's GJ kept rows in LDS
// (stride-36): 8 conflicted b128 row ops + a conflicted pivot-col read per
// iteration, on a 32-step serial LDS chain, x2 passes -> 23% of all CU cycles
// were bank-conflict cycles. Now each lane pair keeps its half-row in VGPRs
// (seeded directly from the X1 matmul accumulators); per unrolled iteration
// only the pivot row goes through LDS: owner pair publishes 36 floats to PB
// (R1 tail, no LDS growth), everyone reads them back as uniform broadcasts.
// f = own-row element k (static reg index under full unroll, pair-shared via
// one DPP xor1 add); d = PB[k] broadcast. Zero GJ bank conflicts, one LDS
// round-trip per iteration. Inertia/fallback semantics unchanged.
//
// Round 10 (kept): partial-spectrum ReEig. rec1 = X1 + sum_{lam<eps}(eps-lam)
// u u^T via inertia count + 2-pass shift-invert + f64 Gram-Schmidt +
// Rayleigh-Ritz; rank-4 correction applied in the 16-dim M2 space.
// mneg>4 or breakdown -> original jac32. Stage 2: f64 chol certificate
// (passes) + jac16 fallback. Stage 3: serial 4x4 Jacobi + LogEig + fc.

#define MAXSW32 8
#define MAXSW16 8
#define MAXSW4  8
#define JTOL2   1e-12f
#define EPS_REC 1e-4f
#define SHIFT1  4e-4f
#define BRKTOL  1e-7f
#define DELTA2  2e-4

// Compiler-only memory fence (single-wave block: LDS is HW-ordered per wave).
#define CFENCE() asm volatile("" ::: "memory")

__device__ __forceinline__ float shfl_xor_f(float v, int m) { return __shfl_xor(v, m, 64); }
__device__ __forceinline__ float dot4(float4 a, float4 b) {
  return a.x * b.x + a.y * b.y + a.z * b.z + a.w * b.w;
}
__device__ __forceinline__ void axpy4(float4& a, float xv, float4 w) {
  a.x += xv * w.x; a.y += xv * w.y; a.z += xv * w.z; a.w += xv * w.w;
}

// DPP lane-exchange adds (VALU pipe, no DS traffic).
__device__ __forceinline__ float dpp_add_xor1(float d) {
  return d + __int_as_float(__builtin_amdgcn_mov_dpp(__float_as_int(d), 0xB1, 0xF, 0xF, true));
}
__device__ __forceinline__ float dpp_add_xor2(float d) {
  return d + __int_as_float(__builtin_amdgcn_mov_dpp(__float_as_int(d), 0x4E, 0xF, 0xF, true));
}
__device__ __forceinline__ float dpp_add_halfmirror(float d) {  // completes 8-lane sum
  return d + __int_as_float(__builtin_amdgcn_mov_dpp(__float_as_int(d), 0x141, 0xF, 0xF, true));
}

// f64 sum over lanes 0..31 (callers keep sources within the active half).
__device__ __forceinline__ double wsum32(double v) {
  #pragma unroll
  for (int m = 1; m <= 16; m <<= 1) v += __shfl_xor(v, m, 64);
  return v;
}
__device__ __forceinline__ float wmax64(float v) {
  #pragma unroll
  for (int m = 1; m <= 32; m <<= 1) v = fmaxf(v, __shfl_xor(v, m, 64));
  return v;
}

// Jacobi rotation from off-diag dot d and norms dpp,dqq. Divide-free.
__device__ __forceinline__ void rot_cs(float d, float dpp, float dqq,
                                       float& c, float& s) {
  float tau = 0.5f * (dqq - dpp);
  float r   = __builtin_amdgcn_sqrtf(fmaf(tau, tau, d * d));
  float den = fabsf(tau) + r;
  float tnum = __uint_as_float(__float_as_uint(d) ^
                               (__float_as_uint(tau) & 0x80000000u));
  float t = tnum * __builtin_amdgcn_rcpf(den);
  c = __builtin_amdgcn_rsqf(fmaf(t, t, 1.f));
  s = t * c;
}

// Register-resident Gauss-Jordan of A = X1 - SHIFT1*I with 4 RHS in regs.
// Lane pair (kc,h) holds half-row (x0..x3 = X1[kc][hb..hb+15], by symmetry
// also column kc). Pivot row published through PB[36] (LDS, broadcast reads).
// On exit: y = eliminated RHS (divide by down for the solution), down = own
// pivot, mneg = #(pivots<=0), brk = tiny/NaN pivot encountered.
__device__ __forceinline__ void gj_reg(float4 x0, float4 x1, float4 x2, float4 x3,
                                       float* __restrict__ PB,
                                       int kc, int h, int hb, float maxd,
                                       float4& y, float& down,
                                       int& mneg, bool& brk) {
  float4 r0 = x0, r1 = x1, r2 = x2, r3 = x3;
  const int dc = kc - hb;      // own diagonal column within this half (0..15)
  r0.x -= (dc == 0)  ? SHIFT1 : 0.f;
  r0.y -= (dc == 1)  ? SHIFT1 : 0.f;
  r0.z -= (dc == 2)  ? SHIFT1 : 0.f;
  r0.w -= (dc == 3)  ? SHIFT1 : 0.f;
  r1.x -= (dc == 4)  ? SHIFT1 : 0.f;
  r1.y -= (dc == 5)  ? SHIFT1 : 0.f;
  r1.z -= (dc == 6)  ? SHIFT1 : 0.f;
  r1.w -= (dc == 7)  ? SHIFT1 : 0.f;
  r2.x -= (dc == 8)  ? SHIFT1 : 0.f;
  r2.y -= (dc == 9)  ? SHIFT1 : 0.f;
  r2.z -= (dc == 10) ? SHIFT1 : 0.f;
  r2.w -= (dc == 11) ? SHIFT1 : 0.f;
  r3.x -= (dc == 12) ? SHIFT1 : 0.f;
  r3.y -= (dc == 13) ? SHIFT1 : 0.f;
  r3.z -= (dc == 14) ? SHIFT1 : 0.f;
  r3.w -= (dc == 15) ? SHIFT1 : 0.f;

  mneg = 0; brk = false; down = 1.f;
  #pragma unroll
  for (int k = 0; k < 32; ++k) {
    if (kc == k) {                       // owner pair publishes pivot row+RHS
      *(float4*)(PB + hb)      = r0;
      *(float4*)(PB + hb + 4)  = r1;
      *(float4*)(PB + hb + 8)  = r2;
      *(float4*)(PB + hb + 12) = r3;
      if (h == 0) *(float4*)(PB + 32) = y;
    }
    CFENCE();
    const float  d  = PB[k];             // uniform broadcast
    const float4 p0 = *(const float4*)(PB + hb);
    const float4 p1 = *(const float4*)(PB + hb + 4);
    const float4 p2 = *(const float4*)(PB + hb + 8);
    const float4 p3 = *(const float4*)(PB + hb + 12);
    const float4 py = *(const float4*)(PB + 32);
    CFENCE();
    mneg += (d <= 0.f) ? 1 : 0;
    brk = brk || !(fabsf(d) >= BRKTOL * maxd);
    // own-row element at column k (k is compile-time under full unroll)
    float elt;
    {
      const int q = (k >> 2) & 3;
      const float4 rq = (q == 0) ? r0 : (q == 1) ? r1 : (q == 2) ? r2 : r3;
      const int m = k & 3;
      elt = (m == 0) ? rq.x : (m == 1) ? rq.y : (m == 2) ? rq.z : rq.w;
    }
    const bool ownhalf = (k >= 16) ? (h == 1) : (h == 0);
    float tm = ownhalf ? elt : 0.f;
    float f  = dpp_add_xor1(tm);         // share across the lane pair
    float fr = f * __builtin_amdgcn_rcpf(d);
    fr   = (brk || (kc == k)) ? 0.f : fr;
    down = (kc == k) ? d : down;
    axpy4(r0, -fr, p0);
    axpy4(r1, -fr, p1);
    axpy4(r2, -fr, p2);
    axpy4(r3, -fr, p3);
    axpy4(y,  -fr, py);
  }
}

// One-sided Jacobi, n=32, column stride 36. 16 pairs x 4 lanes.
__device__ __forceinline__ void jac32(float* __restrict__ G, float* __restrict__ nrm,
                                      int lane) {
  const int kq  = lane >> 2, sub = lane & 3;
  const int k = (kq & 8) | ((kq & 1) << 2) | (kq & 2) | ((kq & 4) >> 2);
  const int o0 = 4 * sub, o1 = 4 * sub + 16;
  int pp = (k == 0) ? 31 : k;
  int qq = (k == 0) ? 0 : (31 - k);
  for (int sw = 0; sw < MAXSW32; ++sw) {
    bool anyact = false;
    for (int r = 0; r < 31; ++r) {
      CFENCE();
      const int p = pp, q = qq;
      if (k != 0) { pp += 16; if (pp >= 31) pp -= 31; }
      qq += 16; if (qq >= 31) qq -= 31;
      const int pb = p * 36, qb = q * 36;
      float dpp = nrm[p], dqq = nrm[q];
      float4 gp0 = *(const float4*)(G + pb + o0);
      float4 gp1 = *(const float4*)(G + pb + o1);
      float4 gq0 = *(const float4*)(G + qb + o0);
      float4 gq1 = *(const float4*)(G + qb + o1);
      float d = dot4(gp0, gq0) + dot4(gp1, gq1);
      d = dpp_add_xor1(d);
      d = dpp_add_xor2(d);
      bool active = (d * d > JTOL2 * dpp * dqq);
      if (__ballot(active) == 0ull) continue;
      anyact = true;
      if (active) {
        float c, s;
        rot_cs(d, dpp, dqq, c, s);
        float4 np0, np1, nq0, nq1;
        np0.x = c * gp0.x - s * gq0.x; nq0.x = s * gp0.x + c * gq0.x;
        np0.y = c * gp0.y - s * gq0.y; nq0.y = s * gp0.y + c * gq0.y;
        np0.z = c * gp0.z - s * gq0.z; nq0.z = s * gp0.z + c * gq0.z;
        np0.w = c * gp0.w - s * gq0.w; nq0.w = s * gp0.w + c * gq0.w;
        np1.x = c * gp1.x - s * gq1.x; nq1.x = s * gp1.x + c * gq1.x;
        np1.y = c * gp1.y - s * gq1.y; nq1.y = s * gp1.y + c * gq1.y;
        np1.z = c * gp1.z - s * gq1.z; nq1.z = s * gp1.z + c * gq1.z;
        np1.w = c * gp1.w - s * gq1.w; nq1.w = s * gp1.w + c * gq1.w;
        *(float4*)(G + pb + o0) = np0;
        *(float4*)(G + pb + o1) = np1;
        *(float4*)(G + qb + o0) = nq0;
        *(float4*)(G + qb + o1) = nq1;
        if (sub == 0) {
          float cs2 = 2.f * c * s * d, cc = c * c, ss = s * s;
          nrm[p] = cc * dpp - cs2 + ss * dqq;
          nrm[q] = ss * dpp + cs2 + cc * dqq;
        }
      }
    }
    if (!anyact) break;
  }
  __syncthreads();
}

// One-sided Jacobi, n=16, column stride 20. 8 pairs x 8 lanes.
__device__ __forceinline__ void jac16(float* __restrict__ G, float* __restrict__ nrm,
                                      int lane) {
  const int kq = lane >> 3, sub = lane & 7;
  const int k = (kq >> 1) | ((kq & 1) << 2);   // 0,4,1,5,2,6,3,7
  const int o = 2 * sub;
  int pp = (k == 0) ? 15 : k;
  int qq = (k == 0) ? 0 : (15 - k);
  for (int sw = 0; sw < MAXSW16; ++sw) {
    bool anyact = false;
    for (int r = 0; r < 15; ++r) {
      CFENCE();
      const int p = pp, q = qq;
      if (k != 0) { pp += 8; if (pp >= 15) pp -= 15; }
      qq += 8; if (qq >= 15) qq -= 15;
      const int pb = p * 20 + o, qb = q * 20 + o;
      float dpp = nrm[p], dqq = nrm[q];
      float2 gp = *(const float2*)(G + pb);
      float2 gq = *(const float2*)(G + qb);
      float d = gp.x * gq.x + gp.y * gq.y;
      d = dpp_add_xor1(d);
      d = dpp_add_xor2(d);
      d = dpp_add_halfmirror(d);
      bool active = (d * d > JTOL2 * dpp * dqq);
      if (__ballot(active) == 0ull) continue;
      anyact = true;
      if (active) {
        float c, s;
        rot_cs(d, dpp, dqq, c, s);
        float2 np, nq;
        np.x = c * gp.x - s * gq.x; nq.x = s * gp.x + c * gq.x;
        np.y = c * gp.y - s * gq.y; nq.y = s * gp.y + c * gq.y;
        *(float2*)(G + pb) = np;
        *(float2*)(G + qb) = nq;
        if (sub == 0) {
          float cs2 = 2.f * c * s * d, cc = c * c, ss = s * s;
          nrm[p] = cc * dpp - cs2 + ss * dqq;
          nrm[q] = ss * dpp + cs2 + cc * dqq;
        }
      }
    }
    if (!anyact) break;
  }
  __syncthreads();
}

__launch_bounds__(64, 4)
__global__ void spdnet_kernel(const float* __restrict__ x,
                              const float* __restrict__ w1,
                              const float* __restrict__ w2,
                              const float* __restrict__ w3,
                              const float* __restrict__ fcw,
                              float* __restrict__ out,
                              int B) {
  const int b    = blockIdx.x;
  const int lane = threadIdx.x;

  // R0: x -> L -> X1 (32x36) -> [M2 16x20 | F 32x20 @320 | V/TQ @960 | w3s @1024]
  // R1: w1 (dead after X1) -> Q in holes (j*36+32) + PB @1152 -> w2s [0..576) + E/Z @576
  __shared__ __align__(16) float R0[1152];
  __shared__ __align__(16) float R1[1216];
  __shared__ __align__(16) float NRM[32];

  const float* xb = x + (size_t)b * 1024;
  const int kc = lane >> 1, h = lane & 1, hb = h * 16;

  // ---- stage x -> R0, w1 -> R1 (both row-major, stride 36) ----
  #pragma unroll
  for (int t = 0; t < 4; ++t) {
    int i4 = lane + 64 * t;
    int r = i4 >> 3, c4 = i4 & 7;
    float4 xv = ((const float4*)xb)[i4];
    float4 wv = ((const float4*)w1)[i4];
    *(float4*)(R0 + r * 36 + 4 * c4) = xv;
    *(float4*)(R1 + r * 36 + 4 * c4) = wv;
  }
  float w3r = w3[lane];
  __syncthreads();

  // ---- L = x * w1 in registers: lane (kc,h) owns half-column kc ----
  float4 a0 = {0.f, 0.f, 0.f, 0.f}, a1 = a0, a2 = a0, a3 = a0;
  #pragma unroll
  for (int j = 0; j < 32; ++j) {
    float wv = R1[j * 36 + kc];
    const float* xc = R0 + j * 36 + hb;
    axpy4(a0, wv, *(const float4*)(xc));
    axpy4(a1, wv, *(const float4*)(xc + 4));
    axpy4(a2, wv, *(const float4*)(xc + 8));
    axpy4(a3, wv, *(const float4*)(xc + 12));
  }
  __syncthreads();
  *(float4*)(R0 + kc * 36 + hb)      = a0;
  *(float4*)(R0 + kc * 36 + hb + 4)  = a1;
  *(float4*)(R0 + kc * 36 + hb + 8)  = a2;
  *(float4*)(R0 + kc * 36 + hb + 12) = a3;
  __syncthreads();

  // ---- X1[:,kc] = sum_k w1[k][:] * L[k][kc] ----
  float Lc[32];
  #pragma unroll
  for (int c4 = 0; c4 < 8; ++c4) {
    float4 v = *(const float4*)(R0 + kc * 36 + 4 * c4);
    Lc[4 * c4] = v.x; Lc[4 * c4 + 1] = v.y; Lc[4 * c4 + 2] = v.z; Lc[4 * c4 + 3] = v.w;
  }
  a0 = {0.f, 0.f, 0.f, 0.f}; a1 = a0; a2 = a0; a3 = a0;
  #pragma unroll
  for (int kk = 0; kk < 32; ++kk) {
    float lv = Lc[kk];
    const float* wr = R1 + kk * 36 + hb;
    axpy4(a0, lv, *(const float4*)(wr));
    axpy4(a1, lv, *(const float4*)(wr + 4));
    axpy4(a2, lv, *(const float4*)(wr + 8));
    axpy4(a3, lv, *(const float4*)(wr + 12));
  }
  float nv = dot4(a0, a0) + dot4(a1, a1) + dot4(a2, a2) + dot4(a3, a3);
  nv += shfl_xor_f(nv, 1);
  __syncthreads();
  *(float4*)(R0 + kc * 36 + hb)      = a0;
  *(float4*)(R0 + kc * 36 + hb + 4)  = a1;
  *(float4*)(R0 + kc * 36 + hb + 8)  = a2;
  *(float4*)(R0 + kc * 36 + hb + 12) = a3;
  if (h == 0) NRM[kc] = nv;
  __syncthreads();

  // ---- inertia + shift-invert pass 1 (rows in registers; a0..a3 = X1 half-row) ----
  float maxd = wmax64(R0[kc * 36 + kc]);
  float* PB = R1 + 1152;
  float4 yv;
  {
    unsigned s = kc * 0x9E3779B9u + 0x7F4A7C15u;
    s = s * 1664525u + 1013904223u; yv.x = (float)(int)(s >> 16) - 32768.f;
    s = s * 1664525u + 1013904223u; yv.y = (float)(int)(s >> 16) - 32768.f;
    s = s * 1664525u + 1013904223u; yv.z = (float)(int)(s >> 16) - 32768.f;
    s = s * 1664525u + 1013904223u; yv.w = (float)(int)(s >> 16) - 32768.f;
  }
  int mneg; bool brk; float down;
  gj_reg(a0, a1, a2, a3, PB, kc, h, hb, maxd, yv, down, mneg, brk);
  const bool doeig  = brk || (mneg > 4);
  const bool docorr = !doeig && (mneg >= 1);

  if (docorr) {
    // ---- pass 2 (refine), then f64 GS + Rayleigh-Ritz on the 4-dim block ----
    float rd1 = __builtin_amdgcn_rcpf(down);
    float4 y1 = make_float4(yv.x * rd1, yv.y * rd1, yv.z * rd1, yv.w * rd1);
    int mn2; bool b2; float down2;
    gj_reg(a0, a1, a2, a3, PB, kc, h, hb, maxd, y1, down2, mn2, b2);
    (void)mn2; (void)b2;
    float rd2 = __builtin_amdgcn_rcpf(down2);
    if (h == 0)
      *(float4*)(R1 + kc * 36 + 32) =
          make_float4(y1.x * rd2, y1.y * rd2, y1.z * rd2, y1.w * rd2);
    CFENCE();
    if (lane < 32) {
      const int j = lane;
      float4 cv = *(const float4*)(R1 + j * 36 + 32);
      double y0 = (double)cv.x, yy1 = (double)cv.y;
      double y2 = (double)cv.z, y3 = (double)cv.w;
      double n, pr;
      double q0, q1, q2, q3;
      n = wsum32(y0 * y0); q0 = y0 * (1.0 / sqrt(n + 1e-280));
      pr = wsum32(q0 * yy1); yy1 -= pr * q0;
      n = wsum32(yy1 * yy1); q1 = yy1 * (1.0 / sqrt(n + 1e-280));
      pr = wsum32(q0 * y2); y2 -= pr * q0;
      pr = wsum32(q1 * y2); y2 -= pr * q1;
      n = wsum32(y2 * y2); q2 = y2 * (1.0 / sqrt(n + 1e-280));
      pr = wsum32(q0 * y3); y3 -= pr * q0;
      pr = wsum32(q1 * y3); y3 -= pr * q1;
      pr = wsum32(q2 * y3); y3 -= pr * q2;
      n = wsum32(y3 * y3); q3 = y3 * (1.0 / sqrt(n + 1e-280));
      CFENCE();
      *(float4*)(R1 + j * 36 + 32) =
          make_float4((float)q0, (float)q1, (float)q2, (float)q3);
      CFENCE();
      // T = X1 * Q (f64 accumulation; X1 symmetric so use row j)
      double T0 = 0, T1 = 0, T2 = 0, T3 = 0;
      #pragma unroll 4
      for (int i = 0; i < 32; ++i) {
        float4 qv = *(const float4*)(R1 + i * 36 + 32);   // uniform -> broadcast
        double xji = (double)R0[j * 36 + i];
        T0 += xji * qv.x; T1 += xji * qv.y; T2 += xji * qv.z; T3 += xji * qv.w;
      }
      double S00 = wsum32(q0 * T0), S10 = wsum32(q1 * T0);
      double S20 = wsum32(q2 * T0), S30 = wsum32(q3 * T0);
      double S11 = wsum32(q1 * T1), S21 = wsum32(q2 * T1), S31 = wsum32(q3 * T1);
      double S22 = wsum32(q2 * T2), S32 = wsum32(q3 * T2);
      double S33 = wsum32(q3 * T3);
      if (lane == 0) {
        double Ad[4][4] = {{S00, S10, S20, S30}, {S10, S11, S21, S31},
                           {S20, S21, S22, S32}, {S30, S31, S32, S33}};
        float Wd[4][4] = {{1.f, 0.f, 0.f, 0.f}, {0.f, 1.f, 0.f, 0.f},
                          {0.f, 0.f, 1.f, 0.f}, {0.f, 0.f, 0.f, 1.f}};
        for (int sw = 0; sw < 5; ++sw) {
          #pragma unroll
          for (int p = 0; p < 3; ++p) {
            #pragma unroll
            for (int q = p + 1; q < 4; ++q) {
              double apq = Ad[p][q];
              if (fabs(apq) > 1e-14 * (fabs(Ad[p][p]) + fabs(Ad[q][q])) + 1e-300) {
                double tau = 0.5 * (Ad[q][q] - Ad[p][p]);
                double rr = sqrt(tau * tau + apq * apq);
                double t = ((tau >= 0.0) ? apq : -apq) / (fabs(tau) + rr);
                double c = 1.0 / sqrt(t * t + 1.0), sv = t * c;
                #pragma unroll
                for (int jj = 0; jj < 4; ++jj) {
                  double ap = Ad[p][jj], aq = Ad[q][jj];
                  Ad[p][jj] = c * ap - sv * aq;
                  Ad[q][jj] = sv * ap + c * aq;
                }
                #pragma unroll
                for (int ii = 0; ii < 4; ++ii) {
                  double ap = Ad[ii][p], aq = Ad[ii][q];
                  Ad[ii][p] = c * ap - sv * aq;
                  Ad[ii][q] = sv * ap + c * aq;
                  float wp = Wd[ii][p], wq = Wd[ii][q];
                  Wd[ii][p] = (float)(c * wp - sv * wq);
                  Wd[ii][q] = (float)(sv * wp + c * wq);
                }
              }
            }
          }
        }
        #pragma unroll
        for (int qi = 0; qi < 4; ++qi) {
          NRM[16 + qi] = (float)Ad[qi][qi];        // theta
          #pragma unroll
          for (int ai = 0; ai < 4; ++ai) NRM[ai * 4 + qi] = Wd[ai][qi];
        }
      }
    }
    __syncthreads();
  }

  if (doeig) {
    // ---- fallback: full one-sided Jacobi on X1 (NRM intact) ----
    jac32(R0, NRM, lane);
  }

  // ---- stage w2 into R1[0..576) (holes at j*36+32 survive) ----
  #pragma unroll
  for (int t = 0; t < 8; ++t) {
    int idx = lane + 64 * t;
    int j = idx >> 4, a = idx & 15;
    R1[a * 36 + j] = w2[idx];
  }
  __syncthreads();

  if (!doeig) {
    // ---- TQ = w2^T Q (regs; Q holes + w2 both in R1, disjoint) ----
    float tq = 0.f;
    if (docorr) {
      const int aq = lane >> 4, a16 = lane & 15;
      #pragma unroll 4
      for (int j = 0; j < 32; ++j)
        tq += R1[a16 * 36 + j] * R1[j * 36 + 32 + aq];
      CFENCE();
    }
    // ---- E[a][k] = w2_a . x1_k -> R1+576 (rec1 base = X1) ----
    {
      float g[16];
      #pragma unroll
      for (int c = 0; c < 4; ++c) {
        float4 v = *(const float4*)(R0 + kc * 36 + hb + 4 * c);
        g[4 * c] = v.x; g[4 * c + 1] = v.y; g[4 * c + 2] = v.z; g[4 * c + 3] = v.w;
      }
      #pragma unroll
      for (int a = 0; a < 16; ++a) {
        const float* wr = R1 + a * 36 + hb;
        float part = 0.f;
        #pragma unroll
        for (int c = 0; c < 4; ++c) {
          float4 wv = *(const float4*)(wr + 4 * c);
          part += g[4 * c] * wv.x + g[4 * c + 1] * wv.y + g[4 * c + 2] * wv.z + g[4 * c + 3] * wv.w;
        }
        part = dpp_add_xor1(part);
        if (h == 0) R1[576 + kc * 20 + a] = part;
      }
    }
    __syncthreads();                      // all X1 reads done
    if (docorr) {
      // ---- V[a][q] = sqrt((eps-theta_q)+) * sum_aq TQ[a][aq] W[aq][q] ----
      R0[960 + lane] = tq;                // TQ[a16][aq] @ 960+aq*16+a16
      CFENCE();
      if (lane < 16) {
        float t0 = R0[960 + lane], t1 = R0[976 + lane];
        float t2 = R0[992 + lane], t3 = R0[1008 + lane];
        float4 vv;
        {
          float cs = __builtin_amdgcn_sqrtf(fmaxf(EPS_REC - NRM[16], 0.f));
          vv.x = cs * (t0 * NRM[0] + t1 * NRM[4] + t2 * NRM[8] + t3 * NRM[12]);
        }
        {
          float cs = __builtin_amdgcn_sqrtf(fmaxf(EPS_REC - NRM[17], 0.f));
          vv.y = cs * (t0 * NRM[1] + t1 * NRM[5] + t2 * NRM[9] + t3 * NRM[13]);
        }
        {
          float cs = __builtin_amdgcn_sqrtf(fmaxf(EPS_REC - NRM[18], 0.f));
          vv.z = cs * (t0 * NRM[2] + t1 * NRM[6] + t2 * NRM[10] + t3 * NRM[14]);
        }
        {
          float cs = __builtin_amdgcn_sqrtf(fmaxf(EPS_REC - NRM[19], 0.f));
          vv.w = cs * (t0 * NRM[3] + t1 * NRM[7] + t2 * NRM[11] + t3 * NRM[15]);
        }
        CFENCE();
        *(float4*)(R0 + 960 + lane * 4) = vv;   // V rows, float4 each
      }
      CFENCE();
    }
    // ---- F = w2 row-major @ R0+320 (X1 dead now) ----
    #pragma unroll
    for (int t = 0; t < 8; ++t) {
      int idx = lane + 64 * t;
      int j = idx >> 4, a2 = idx & 15;
      R0[320 + j * 20 + a2] = R1[a2 * 36 + j];
    }
    __syncthreads();
  } else {
    // ---- SLOW stage 1: Z[:,k] = (w2^T g_k) * sqrt(mu)/lam ----
    {
      float g[16];
      #pragma unroll
      for (int c = 0; c < 4; ++c) {
        float4 v = *(const float4*)(R0 + kc * 36 + hb + 4 * c);
        g[4 * c] = v.x; g[4 * c + 1] = v.y; g[4 * c + 2] = v.z; g[4 * c + 3] = v.w;
      }
      float dpp = 0.f;
      #pragma unroll
      for (int i = 0; i < 16; ++i) dpp += g[i] * g[i];
      dpp += shfl_xor_f(dpp, 1);
      float lam = __builtin_amdgcn_sqrtf(dpp);
      float mu  = fmaxf(lam, 1e-4f);
      float sc  = __builtin_amdgcn_sqrtf(mu) * __builtin_amdgcn_rcpf(fmaxf(lam, 1e-30f));
      #pragma unroll
      for (int a = 0; a < 16; ++a) {
        const float* wr = R1 + a * 36 + hb;
        float part = 0.f;
        #pragma unroll
        for (int c = 0; c < 4; ++c) {
          float4 wv = *(const float4*)(wr + 4 * c);
          part += g[4 * c] * wv.x + g[4 * c + 1] * wv.y + g[4 * c + 2] * wv.z + g[4 * c + 3] * wv.w;
        }
        part = dpp_add_xor1(part);
        if (h == 0) R1[576 + kc * 20 + a] = part * sc;
      }
    }
    __syncthreads();
  }

  // ---- M2 (16x16) into R0 stride 20 (+rank-4 correction); stage w3 @1024 ----
  {
    const int a = lane & 15, b0i = (lane >> 4) * 4;
    const float* zbb = doeig ? (R1 + 576) : (R0 + 320);
    float m0 = 0.f, m1 = 0.f, m2 = 0.f, m3 = 0.f;
    #pragma unroll
    for (int kk = 0; kk < 32; ++kk) {
      float za = R1[576 + kk * 20 + a];
      float4 zb = *(const float4*)(zbb + kk * 20 + b0i);
      m0 += za * zb.x; m1 += za * zb.y; m2 += za * zb.z; m3 += za * zb.w;
    }
    if (docorr) {
      float4 va = *(const float4*)(R0 + 960 + a * 4);
      float4 v0 = *(const float4*)(R0 + 960 + (b0i + 0) * 4);
      float4 v1 = *(const float4*)(R0 + 960 + (b0i + 1) * 4);
      float4 v2 = *(const float4*)(R0 + 960 + (b0i + 2) * 4);
      float4 v3 = *(const float4*)(R0 + 960 + (b0i + 3) * 4);
      m0 += dot4(va, v0); m1 += dot4(va, v1);
      m2 += dot4(va, v2); m3 += dot4(va, v3);
    }
    R0[(b0i + 0) * 20 + a] = m0;
    R0[(b0i + 1) * 20 + a] = m1;
    R0[(b0i + 2) * 20 + a] = m2;
    R0[(b0i + 3) * 20 + a] = m3;
    R0[1024 + (lane & 3) * 20 + (lane >> 2)] = w3r;   // w3 col-major
  }
  __syncthreads();

  // ---- norms of M2 columns (slow path needs them; cheap) ----
  if (lane < 32) {
    int cc = lane >> 1;
    float4 v0 = *(const float4*)(R0 + cc * 20 + 8 * h);
    float4 v1 = *(const float4*)(R0 + cc * 20 + 8 * h + 4);
    float n2 = dot4(v0, v0) + dot4(v1, v1);
    n2 += shfl_xor_f(n2, 1);
    if (h == 0) NRM[cc] = n2;
  }
  __syncthreads();

  // ---- chol16 PD certificate on M2, f64 (R1 dead: 320 doubles) ----
  bool fast2 = true;
  {
    double* Cd = (double*)R1;
    const int c16 = lane >> 2, s4 = (lane & 3) * 4;
    #pragma unroll
    for (int r = 0; r < 4; ++r)
      Cd[c16 * 20 + s4 + r] = (double)R0[c16 * 20 + s4 + r];
    CFENCE();
    if (lane < 16) Cd[lane * 20 + lane] -= DELTA2;
    for (int k = 0; k < 16; ++k) {
      CFENCE();
      double d = Cd[k * 20 + k];
      if (!(d > 0.0)) { fast2 = false; break; }
      double rd = 1.0 / d;
      if (c16 > k) {
        double f = Cd[c16 * 20 + k] * rd;
        #pragma unroll
        for (int r = 0; r < 4; ++r)
          Cd[c16 * 20 + s4 + r] -= f * Cd[k * 20 + s4 + r];
      }
    }
  }
  __syncthreads();

  if (fast2) {
    // ---- FAST stage 2: rec2 = M2. Y'[a][k] = w3_a . m2_k; X3 = Y' * w3 ----
    const int k3 = (lane >> 2) & 15, a3 = lane & 3;
    float dotv = 0.f;
    #pragma unroll
    for (int c = 0; c < 4; ++c) {
      float4 gv = *(const float4*)(R0 + k3 * 20 + 4 * c);
      float4 wv = *(const float4*)(R0 + 1024 + a3 * 20 + 4 * c);
      dotv += dot4(gv, wv);
    }
    R1[k3 * 4 + a3] = dotv;
    __syncthreads();
    if (lane < 16) {
      int a = lane >> 2, b2 = lane & 3;
      float s = 0.f;
      #pragma unroll
      for (int kk = 0; kk < 16; ++kk)
        s += R1[kk * 4 + a] * R0[1024 + b2 * 20 + kk];
      R1[64 + lane] = s;
    }
    __syncthreads();
  } else {
    // ---- SLOW stage 2: eig #2 + Y + X3 ----
    jac16(R0, NRM, lane);
    {
      const int k3 = (lane >> 2) & 15, a3 = lane & 3;
      float dpp2 = 0.f, dotv = 0.f;
      #pragma unroll
      for (int c = 0; c < 4; ++c) {
        float4 gv = *(const float4*)(R0 + k3 * 20 + 4 * c);
        float4 wv = *(const float4*)(R0 + 1024 + a3 * 20 + 4 * c);
        dpp2 += dot4(gv, gv);
        dotv += dot4(gv, wv);
      }
      float lam2 = __builtin_amdgcn_sqrtf(dpp2);
      float mu2  = fmaxf(lam2, 1e-4f);
      float sc2  = __builtin_amdgcn_sqrtf(mu2) * __builtin_amdgcn_rcpf(fmaxf(lam2, 1e-30f));
      __syncthreads();
      R1[k3 * 4 + a3] = dotv * sc2;
    }
    __syncthreads();
    if (lane < 16) {
      int a = lane >> 2, b2 = lane & 3;
      float s = 0.f;
      #pragma unroll
      for (int kk = 0; kk < 16; ++kk)
        s += R1[kk * 4 + a] * R1[kk * 4 + b2];
      R1[64 + lane] = s;
    }
    __syncthreads();
  }

  // ---- stage 3: serial 4x4 two-sided Jacobi + LogEig + fc + log_softmax ----
  if (lane == 0) {
    float Am[4][4], V[4][4];
    float maxdg = 0.f;
    #pragma unroll
    for (int i = 0; i < 4; ++i) {
      #pragma unroll
      for (int j = 0; j < 4; ++j) {
        Am[i][j] = R1[64 + i * 4 + j];
        V[i][j] = (i == j) ? 1.f : 0.f;
      }
      maxdg = fmaxf(maxdg, fabsf(Am[i][i]));
    }
    float tol3 = 1e-7f * maxdg;
    for (int sw = 0; sw < MAXSW4; ++sw) {
      bool any = false;
      #pragma unroll
      for (int p = 0; p < 3; ++p) {
        #pragma unroll
        for (int q = p + 1; q < 4; ++q) {
          float apq = Am[p][q];
          if (fabsf(apq) > tol3) {
            any = true;
            float c, sv;
            rot_cs(apq, Am[p][p], Am[q][q], c, sv);
            #pragma unroll
            for (int j = 0; j < 4; ++j) {
              float ap = Am[p][j], aq = Am[q][j];
              Am[p][j] = c * ap - sv * aq;
              Am[q][j] = sv * ap + c * aq;
            }
            #pragma unroll
            for (int i = 0; i < 4; ++i) {
              float ap = Am[i][p], aq = Am[i][q];
              Am[i][p] = c * ap - sv * aq;
              Am[i][q] = sv * ap + c * aq;
              float up = V[i][p], uq = V[i][q];
              V[i][p] = c * up - sv * uq;
              V[i][q] = sv * up + c * uq;
            }
          }
        }
      }
      if (!any) break;
    }
    float lm[4];
    #pragma unroll
    for (int i = 0; i < 4; ++i) lm[i] = logf(fmaxf(Am[i][i], 1e-10f));
    float feat[16];
    #pragma unroll
    for (int i = 0; i < 4; ++i)
      #pragma unroll
      for (int j = 0; j < 4; ++j) {
        float acc2 = 0.f;
        #pragma unroll
        for (int kk = 0; kk < 4; ++kk) acc2 += V[i][kk] * lm[kk] * V[j][kk];
        feat[i * 4 + j] = acc2;
      }
    float z0 = 0.f, z1 = 0.f;
    #pragma unroll
    for (int f = 0; f < 16; ++f) {
      z0 += feat[f] * fcw[f * 2 + 0];
      z1 += feat[f] * fcw[f * 2 + 1];
    }
    float mx = fmaxf(z0, z1);
    float lse = mx + logf(expf(z0 - mx) + expf(z1 - mx));
    out[b * 2 + 0] = z0 - lse;
    out[b * 2 + 1] = z1 - lse;
    float* fo = out + (size_t)2 * B + (size_t)b * 16;
    #pragma unroll
    for (int f = 0; f < 16; ++f) fo[f] = feat[f];
  }
}

extern "C" void kernel_launch(void* const* d_in, const int* in_sizes, int n_in,
                              void* d_out, int out_size, void* d_ws, size_t ws_size,
                              hipStream_t stream) {
  (void)n_in; (void)d_ws; (void)ws_size; (void)out_size;
  const float* x   = (const float*)d_in[0];
  const float* w1  = (const float*)d_in[1];
  const float* w2  = (const float*)d_in[2];
  const float* w3  = (const float*)d_in[3];
  const float* fcw = (const float*)d_in[4];
  float* out = (float*)d_out;
  int B = in_sizes[0] / 1024;
  spdnet_kernel<<<B, 64, 0, stream>>>(x, w1, w2, w3, fcw, out, B);
}